// Round 2
// baseline (247.116 us; speedup 1.0000x reference)
//
#include <hip/hip_runtime.h>

#define NTHREADS 256

typedef __attribute__((ext_vector_type(8))) short bf16x8;
typedef __attribute__((ext_vector_type(4))) float f32x4;

constexpr int kB = 16;
constexpr int kS = 2048;
constexpr int kD = 128;
constexpr int QBLK = 64;
constexpr int KBLK = 64;
constexpr float kNegMax = -3.402823466e38f;

// fp32 -> bf16 round-to-nearest-even (bit trick; inputs are finite)
__device__ __forceinline__ short f2bf(float f) {
    unsigned u = __builtin_bit_cast(unsigned, f);
    u += 0x7FFFu + ((u >> 16) & 1u);
    return (short)(u >> 16);
}

// LDS byte-column swizzle: breaks the 16-way bank conflict of row-major
// D=128/64 tiles read column-wise with ds_read_b128 (guide G4 / T2).
#define SWZ(bytecol, row) ((bytecol) ^ (((row) & 7) << 4))

__global__ __launch_bounds__(NTHREADS, 2)
void attn_fwd(const float* __restrict__ q, const float* __restrict__ k,
              const float* __restrict__ v, const int* __restrict__ mask,
              float* __restrict__ out)
{
    // LDS: K 16K | Vt 16K | P 8K | mask 4K = 44 KiB -> 3 blocks/CU
    __shared__ __align__(16) char smem[45056];
    char* K_lds  = smem;              // [64 kv][128 d] bf16, row stride 256 B, swizzled
    char* VT_lds = smem + 16384;      // [128 d][64 kv] bf16, row stride 128 B, swizzled
    char* P_lds  = smem + 32768;      // [4 waves][16 q][64 kv] bf16, row stride 128 B, swizzled
    unsigned char* M_lds = (unsigned char*)(smem + 40960);  // [64 q][64 kv] bytes

    const int tid  = threadIdx.x;
    const int lane = tid & 63;
    const int w    = tid >> 6;   // wave 0..3, owns q-rows w*16..w*16+15
    const int l15  = lane & 15;
    const int lg   = lane >> 4;  // 0..3

    // XCD-aware swizzle: 512 blocks = 8 XCDs x 64; contiguous q-tiles (and whole
    // batches: 64 tiles = 2 batches) per XCD -> K/V served from per-XCD L2.
    const int bid = (int)blockIdx.x;
    const int swz = (bid & 7) * 64 + (bid >> 3);
    const int b     = swz >> 5;
    const int qbase = (swz & 31) * QBLK;

    // ---- hoist Q fragments (pre-scaled by 1/sqrt(D)) ----
    const float scale = 0.08838834764831845f;
    bf16x8 qf[4];
    {
        const float* qp = q + ((size_t)(b * kS + qbase + w * 16 + l15)) * kD;
        #pragma unroll
        for (int kk = 0; kk < 4; ++kk) {
            const float4* p = (const float4*)(qp + kk * 32 + lg * 8);
            float4 a = p[0], c = p[1];
            bf16x8 f;
            f[0]=f2bf(a.x*scale); f[1]=f2bf(a.y*scale); f[2]=f2bf(a.z*scale); f[3]=f2bf(a.w*scale);
            f[4]=f2bf(c.x*scale); f[5]=f2bf(c.y*scale); f[6]=f2bf(c.z*scale); f[7]=f2bf(c.w*scale);
            qf[kk] = f;
        }
    }

    f32x4 acc[8];
    #pragma unroll
    for (int d = 0; d < 8; ++d) acc[d] = f32x4{0.f, 0.f, 0.f, 0.f};
    float m_r[4] = {kNegMax, kNegMax, kNegMax, kNegMax};
    float l_r[4] = {0.f, 0.f, 0.f, 0.f};

    const float* kbat = k + (size_t)b * kS * kD;
    const float* vbat = v + (size_t)b * kS * kD;
    const int* mbat = mask + ((size_t)b * kS + qbase) * kS;

    for (int kt0 = 0; kt0 < kS; kt0 += KBLK) {
        __syncthreads();  // previous tile's LDS reads done before overwrite

        // ---- stage K tile: fp32 -> bf16, [64][128], swizzled ----
        #pragma unroll
        for (int c = 0; c < 4; ++c) {
            int chunk = c * 256 + tid;          // 1024 chunks of 8 floats
            int row = chunk >> 4, col8 = chunk & 15;
            const float4* p = (const float4*)(kbat + (size_t)(kt0 + row) * kD + col8 * 8);
            float4 a = p[0], bb = p[1];
            bf16x8 f;
            f[0]=f2bf(a.x);  f[1]=f2bf(a.y);  f[2]=f2bf(a.z);  f[3]=f2bf(a.w);
            f[4]=f2bf(bb.x); f[5]=f2bf(bb.y); f[6]=f2bf(bb.z); f[7]=f2bf(bb.w);
            *(bf16x8*)(K_lds + row * 256 + SWZ(col8 * 16, row)) = f;
        }
        // ---- stage V transposed: fp32 [64][128] -> bf16 [128][64], swizzled ----
        #pragma unroll
        for (int c = 0; c < 8; ++c) {
            int fidx = c * 256 + tid;           // 2048 float4 reads
            int r = fidx >> 5, c4 = fidx & 31;
            float4 a = *(const float4*)(vbat + (size_t)(kt0 + r) * kD + c4 * 4);
            #pragma unroll
            for (int j = 0; j < 4; ++j) {
                int drow = c4 * 4 + j;
                *(short*)(VT_lds + drow * 128 + SWZ(r * 2, drow)) = f2bf((&a.x)[j]);
            }
        }
        // ---- stage mask tile [64 q][64 kv] int32 -> bytes, coalesced int4 loads ----
        #pragma unroll
        for (int c = 0; c < 4; ++c) {
            int idx = c * 256 + tid;            // 1024 int4 groups (4096 ints)
            int mrow = idx >> 4, mc4 = idx & 15;
            int4 mv = *(const int4*)(mbat + (size_t)mrow * kS + kt0 + mc4 * 4);
            unsigned pk = (unsigned)(mv.x != 0)
                        | ((unsigned)(mv.y != 0) << 8)
                        | ((unsigned)(mv.z != 0) << 16)
                        | ((unsigned)(mv.w != 0) << 24);
            *(unsigned*)(M_lds + mrow * 64 + mc4 * 4) = pk;
        }
        __syncthreads();

        // ---- S = Q @ K^T (per wave: 16 q-rows x 64 kv) ----
        f32x4 s[4];
        #pragma unroll
        for (int kt = 0; kt < 4; ++kt) {
            f32x4 z = f32x4{0.f, 0.f, 0.f, 0.f};
            int krow = kt * 16 + l15;
            #pragma unroll
            for (int kk = 0; kk < 4; ++kk) {
                bf16x8 kf = *(const bf16x8*)(K_lds + krow * 256 + SWZ(kk * 64 + lg * 16, krow));
                z = __builtin_amdgcn_mfma_f32_16x16x32_bf16(qf[kk], kf, z, 0, 0, 0);
            }
            s[kt] = z;
        }

        // ---- mask + online softmax; lane holds S[row=lg*4+i][col=kt*16+l15] ----
        #pragma unroll
        for (int i = 0; i < 4; ++i) {
            int mrow = w * 16 + lg * 4 + i;
            #pragma unroll
            for (int kt = 0; kt < 4; ++kt) {
                if (M_lds[mrow * 64 + kt * 16 + l15]) s[kt][i] = kNegMax;
            }
            float mx = fmaxf(fmaxf(s[0][i], s[1][i]), fmaxf(s[2][i], s[3][i]));
            mx = fmaxf(mx, __shfl_xor(mx, 1));
            mx = fmaxf(mx, __shfl_xor(mx, 2));
            mx = fmaxf(mx, __shfl_xor(mx, 4));
            mx = fmaxf(mx, __shfl_xor(mx, 8));
            float mnew = fmaxf(m_r[i], mx);
            float corr = __expf(m_r[i] - mnew);
            m_r[i] = mnew;
            float rsum = 0.f;
            int prow = lg * 4 + i;
            #pragma unroll
            for (int kt = 0; kt < 4; ++kt) {
                float p = __expf(s[kt][i] - mnew);
                rsum += p;
                *(short*)(P_lds + w * 2048 + prow * 128 + SWZ((kt * 16 + l15) * 2, prow)) = f2bf(p);
            }
            rsum += __shfl_xor(rsum, 1);
            rsum += __shfl_xor(rsum, 2);
            rsum += __shfl_xor(rsum, 4);
            rsum += __shfl_xor(rsum, 8);
            l_r[i] = l_r[i] * corr + rsum;
            #pragma unroll
            for (int d = 0; d < 8; ++d) acc[d][i] *= corr;
        }

        // ---- O += P @ V (P from own wave's LDS, V^T contiguous b128 reads) ----
        #pragma unroll
        for (int kk = 0; kk < 2; ++kk) {
            bf16x8 pf = *(const bf16x8*)(P_lds + w * 2048 + l15 * 128 + SWZ(kk * 64 + lg * 16, l15));
            #pragma unroll
            for (int d = 0; d < 8; ++d) {
                int vrow = d * 16 + l15;
                bf16x8 vf = *(const bf16x8*)(VT_lds + vrow * 128 + SWZ(kk * 64 + lg * 16, vrow));
                acc[d] = __builtin_amdgcn_mfma_f32_16x16x32_bf16(pf, vf, acc[d], 0, 0, 0);
            }
        }
    }

    // ---- epilogue: normalize and store (lane holds O[row=lg*4+i][col=d*16+l15]) ----
    #pragma unroll
    for (int i = 0; i < 4; ++i) {
        float inv = 1.0f / l_r[i];
        float* op = out + ((size_t)(b * kS + qbase + w * 16 + lg * 4 + i)) * kD + l15;
        #pragma unroll
        for (int d = 0; d < 8; ++d) op[d * 16] = acc[d][i] * inv;
    }
}

extern "C" void kernel_launch(void* const* d_in, const int* in_sizes, int n_in,
                              void* d_out, int out_size, void* d_ws, size_t ws_size,
                              hipStream_t stream) {
    const float* q = (const float*)d_in[0];
    const float* k = (const float*)d_in[1];
    const float* v = (const float*)d_in[2];
    const int* mask = (const int*)d_in[3];
    float* out = (float*)d_out;
    dim3 grid(kB * (kS / QBLK));   // 512 blocks
    dim3 block(NTHREADS);
    attn_fwd<<<grid, block, 0, stream>>>(q, k, v, mask, out);
}